// Round 1
// baseline (128.118 us; speedup 1.0000x reference)
//
#include <hip/hip_runtime.h>

// 3-level db4 wavedec (periodization) along axis 1 of (B=64, N=4096, F=64) f32.
// c[b,k,f] = sum_j filt[j] * in[b, (2k+1-j) mod N, f]
// Output rows: [0,512)=cA3, [512,1024)=cD3, [1024,2048)=cD2, [2048,4096)=cD1.

#define FV 16  // F/4 float4 elements per row (F=64)

__global__ __launch_bounds__(256) void dwt_level_kernel(
    const float* __restrict__ in,   // (B, N, 64)
    float* __restrict__ outA,       // (B, aRows, 64), cA written at row aOff+k
    float* __restrict__ outD,       // (B, dRows, 64), cD written at row dOff+k
    int N, int log2HalfN,
    int aRows, int aOff,
    int dRows, int dOff)
{
    const float LO[8] = {
        -0.010597401784997278f,  0.032883011666982945f,
         0.030841381835986965f, -0.18703481171888114f,
        -0.02798376941698385f,   0.6308807679295904f,
         0.7148465705525415f,    0.23037781330885523f};
    // HI[j] = LO[7-j] * signs[j], signs = {-1,1,-1,1,-1,1,-1,1}
    const float HI[8] = {
        -0.23037781330885523f,   0.7148465705525415f,
        -0.6308807679295904f,   -0.02798376941698385f,
         0.18703481171888114f,   0.030841381835986965f,
        -0.032883011666982945f, -0.010597401784997278f};

    const int halfN = 1 << log2HalfN;
    const int idx = blockIdx.x * blockDim.x + threadIdx.x;
    const int f4 = idx & (FV - 1);
    const int kb = idx >> 4;           // FV = 16
    const int k  = kb & (halfN - 1);
    const int b  = kb >> log2HalfN;

    const float4* inB = reinterpret_cast<const float4*>(in) + (size_t)b * N * FV;

    float4 a = make_float4(0.f, 0.f, 0.f, 0.f);
    float4 d = make_float4(0.f, 0.f, 0.f, 0.f);

    const int r0 = 2 * k + 1;
#pragma unroll
    for (int j = 0; j < 8; ++j) {
        int r = r0 - j;
        if (r < 0) r += N;              // periodization wrap (r0-j >= -6)
        const float4 v = inB[(size_t)r * FV + f4];
        a.x = fmaf(LO[j], v.x, a.x);
        a.y = fmaf(LO[j], v.y, a.y);
        a.z = fmaf(LO[j], v.z, a.z);
        a.w = fmaf(LO[j], v.w, a.w);
        d.x = fmaf(HI[j], v.x, d.x);
        d.y = fmaf(HI[j], v.y, d.y);
        d.z = fmaf(HI[j], v.z, d.z);
        d.w = fmaf(HI[j], v.w, d.w);
    }

    reinterpret_cast<float4*>(outA)[((size_t)b * aRows + aOff + k) * FV + f4] = a;
    reinterpret_cast<float4*>(outD)[((size_t)b * dRows + dOff + k) * FV + f4] = d;
}

extern "C" void kernel_launch(void* const* d_in, const int* in_sizes, int n_in,
                              void* d_out, int out_size, void* d_ws, size_t ws_size,
                              hipStream_t stream) {
    (void)in_sizes; (void)n_in; (void)out_size; (void)ws_size;

    const float* x = (const float*)d_in[0];
    float* out = (float*)d_out;
    float* ws  = (float*)d_ws;

    const int B = 64, F = 64;
    // Workspace layout: cA1 = B*2048*F floats (32 MiB), cA2 = B*1024*F (16 MiB)
    float* cA1 = ws;
    float* cA2 = ws + (size_t)B * 2048 * F;

    // Pass 1: N=4096 -> cA1 (ws), cD1 -> out rows [2048, 4096)
    {
        const int total = B * 2048 * FV;  // 2,097,152 -> 8192 blocks
        dwt_level_kernel<<<total / 256, 256, 0, stream>>>(
            x, cA1, out, 4096, 11, 2048, 0, 4096, 2048);
    }
    // Pass 2: N=2048 -> cA2 (ws), cD2 -> out rows [1024, 2048)
    {
        const int total = B * 1024 * FV;  // 4096 blocks
        dwt_level_kernel<<<total / 256, 256, 0, stream>>>(
            cA1, cA2, out, 2048, 10, 1024, 0, 4096, 1024);
    }
    // Pass 3: N=1024 -> cA3 -> out rows [0,512), cD3 -> out rows [512,1024)
    {
        const int total = B * 512 * FV;   // 2048 blocks
        dwt_level_kernel<<<total / 256, 256, 0, stream>>>(
            cA2, out, out, 1024, 9, 4096, 0, 4096, 512);
    }
}

// Round 3
// 117.087 us; speedup vs baseline: 1.0942x; 1.0942x over previous
//
#include <hip/hip_runtime.h>

// Fully fused 3-level db4 wavedec (periodization) over (B=64, N=4096, F=64) f32.
// Per-thread streaming cascade: lane = f (coalesced 256B row loads), each
// thread owns T3=8 level-3 outputs and rolls 8-tap windows through all levels.
// All row indices masked & 4095 (branchless periodic wrap; also makes any
// OOB access structurally impossible).
//
// c[k] = sum_j filt[j] * x[(2k+1-j) mod N]  ==  sum_m w[m]*filtR[m],
// where w[m] = x[(2k-6+m) mod N] and filtR[m] = filt[7-m].
//
// Output rows: [0,512)=cA3, [512,1024)=cD3, [1024,2048)=cD2, [2048,4096)=cD1.

__global__ __launch_bounds__(256) void dwt3_fused(
    const float* __restrict__ in,   // (64, 4096, 64)
    float* __restrict__ out)        // (64, 4096, 64)
{
    // reversed filters (filtR[m] = filt[7-m])
    const float LOR[8] = { 0.23037781330885523f,   0.7148465705525415f,
                           0.6308807679295904f,   -0.02798376941698385f,
                          -0.18703481171888114f,   0.030841381835986965f,
                           0.032883011666982945f, -0.010597401784997278f};
    const float HIR[8] = {-0.010597401784997278f, -0.032883011666982945f,
                           0.030841381835986965f,  0.18703481171888114f,
                          -0.02798376941698385f,  -0.6308807679295904f,
                           0.7148465705525415f,   -0.23037781330885523f};

    const int f    = threadIdx.x & 63;
    const int wv   = threadIdx.x >> 6;             // wave within block
    const int b    = blockIdx.x >> 4;              // 64 batches
    const int tile = (blockIdx.x & 15) * 4 + wv;   // 64 tiles of T3=8 per batch
    const int K3   = tile * 8;

    const float* inB  = in  + (size_t)b * 4096 * 64 + f;
    float*       outB = out + (size_t)b * 4096 * 64 + f;

    const int i1s = 4 * K3 - 18;   // first level-1 index produced (even)

    float w0[8];                       // rolling window x[(2*i1-6 .. 2*i1+1) mod N]
    float w1[8] = {0,0,0,0,0,0,0,0};   // last 8 cA1 values
    float w2[8] = {0,0,0,0,0,0,0,0};   // last 8 cA2 values

    #pragma unroll
    for (int m = 0; m < 8; ++m) {
        const int r = (2 * i1s - 6 + m) & 4095;
        w0[m] = inB[r * 64];
    }

    #pragma unroll
    for (int s = 0; s < 50; ++s) {
        const int i1 = i1s + s;
        if (s > 0) {
            #pragma unroll
            for (int m = 0; m < 6; ++m) w0[m] = w0[m + 2];
            const int ra = (2 * i1)     & 4095;
            const int rb = (2 * i1 + 1) & 4095;
            w0[6] = inB[ra * 64];
            w0[7] = inB[rb * 64];
        }

        // ---- level 1 ----
        float a1 = 0.f;
        #pragma unroll
        for (int m = 0; m < 8; ++m) a1 = fmaf(w0[m], LOR[m], a1);
        if (s >= 18) {                       // i1 in own range [4K3, 4K3+32)
            float d1 = 0.f;
            #pragma unroll
            for (int m = 0; m < 8; ++m) d1 = fmaf(w0[m], HIR[m], d1);
            outB[(size_t)((2048 + i1) & 4095) * 64] = d1;
        }
        #pragma unroll
        for (int m = 0; m < 7; ++m) w1[m] = w1[m + 1];
        w1[7] = a1;

        // ---- level 2: emit when i1 = 2*i2+1 (s odd) and window full ----
        if ((s & 1) && s >= 7) {
            const int i2 = 2 * K3 + (s - 19) / 2;   // exact for odd s
            float a2 = 0.f;
            #pragma unroll
            for (int m = 0; m < 8; ++m) a2 = fmaf(w1[m], LOR[m], a2);
            if (s >= 19) {                   // i2 in own range [2K3, 2K3+16)
                float d2 = 0.f;
                #pragma unroll
                for (int m = 0; m < 8; ++m) d2 = fmaf(w1[m], HIR[m], d2);
                outB[(size_t)((1024 + i2) & 4095) * 64] = d2;
            }
            #pragma unroll
            for (int m = 0; m < 7; ++m) w2[m] = w2[m + 1];
            w2[7] = a2;

            // ---- level 3: emit when i2 = 2*i3+1 and window full ----
            if (s >= 21 && ((s - 21) & 3) == 0) {
                const int i3 = K3 + (s - 21) / 4;    // own range [K3, K3+8)
                float a3 = 0.f, d3 = 0.f;
                #pragma unroll
                for (int m = 0; m < 8; ++m) {
                    a3 = fmaf(w2[m], LOR[m], a3);
                    d3 = fmaf(w2[m], HIR[m], d3);
                }
                outB[(size_t)(i3 & 4095) * 64]           = a3;
                outB[(size_t)((512 + i3) & 4095) * 64]   = d3;
            }
        }
    }
}

extern "C" void kernel_launch(void* const* d_in, const int* in_sizes, int n_in,
                              void* d_out, int out_size, void* d_ws, size_t ws_size,
                              hipStream_t stream) {
    (void)in_sizes; (void)n_in; (void)out_size; (void)d_ws; (void)ws_size;
    const float* x = (const float*)d_in[0];
    float* out = (float*)d_out;
    // 64 batches * 16 block-groups (4 waves/block * 4 tiles each) = 1024 blocks
    dwt3_fused<<<1024, 256, 0, stream>>>(x, out);
}